// Round 4
// baseline (197.779 us; speedup 1.0000x reference)
//
#include <hip/hip_runtime.h>
#include <hip/hip_bf16.h>

#define BATCH   2048
#define NPAR    256
#define NF      32
#define NG      16
#define NBR     4
#define OFS     262144
#define DOUT    128
#define NROWSX  (OFS + NPAR*BATCH)     // 786432 rows of x
#define MROWS   (NPAR*BATCH)           // 524288 parent rows
#define NTILES  (MROWS/16)             // 32768 16-row tiles
#define CHBASE  (NROWSX*NF)            // float offset of children region in out
#define NMLP    1024                   // MLP blocks: 8 waves x 4 tiles each
#define CPN4    (NROWSX*NF/4)          // 6291456 float4 to copy = 12 per thread

typedef short bf16x8 __attribute__((ext_vector_type(8)));   // 8 bf16 bit-patterns
typedef float f32x4  __attribute__((ext_vector_type(4)));

// ws layout (bytes): [0,1MB) G1 f32 | [1MB,+32KB) W2frag bf16 | +8KB W1frag bf16
#define WSOFF_W2F  1048576
#define WSOFF_W1F  (1048576 + 32768)

__device__ __forceinline__ unsigned short f2bf(float f){
  unsigned int u = __float_as_uint(f);
  u += 0x7FFFu + ((u >> 16) & 1u);          // RNE
  return (unsigned short)(u >> 16);
}

// blocks [0,1024): G1[e][j] = b1[j] + sum_k global[e][k] * W1[32+k][j]
// blocks [1024,1034): pack W2 / W1-feature-half into bf16 MFMA fragments.
__global__ void k_g1(const float* __restrict__ gf, const float* __restrict__ W1,
                     const float* __restrict__ b1, const float* __restrict__ W2,
                     char* __restrict__ ws){
  int bid = blockIdx.x, tid = threadIdx.x;
  if (bid < 1024){
    int idx = bid*256 + tid;
    int e = idx >> 7, j = idx & 127;
    float s = b1[j];
    const float* grow = gf + e*NG;
    const float* w = W1 + NF*DOUT + j;
    #pragma unroll
    for (int k = 0; k < NG; k++) s = fmaf(grow[k], w[k*DOUT], s);
    ((float*)ws)[idx] = s;
    return;
  }
  int t = (bid - 1024)*256 + tid;          // 0..2559
  if (t < 2048){
    int f = t >> 6, l = t & 63;
    int kk = f >> 3, n = f & 7;
    int krow = 32*kk + 8*(l >> 4);
    int col  = 16*n + (l & 15);
    union { uint4 q; unsigned short u[8]; } w;
    #pragma unroll
    for (int e = 0; e < 8; e++) w.u[e] = f2bf(W2[(krow + e)*DOUT + col]);
    ((uint4*)(ws + WSOFF_W2F))[t] = w.q;
  } else {
    int q = t - 2048;                      // 0..511
    int n = q >> 6, l = q & 63;
    int kb = 8*(l >> 4);
    int col = 16*n + (l & 15);
    union { uint4 v; unsigned short u[8]; } w;
    #pragma unroll
    for (int e = 0; e < 8; e++) w.u[e] = f2bf(W1[(kb + e)*DOUT + col]);
    ((uint4*)(ws + WSOFF_W1F))[q] = w.v;
  }
}

// Main kernel: 1024 blocks x 512 threads. Every wave: 4 MLP tiles, software
// pipelined, with the x->out copy interleaved (3 float4 per thread per tile).
__global__ __launch_bounds__(512, 4) void k_main(
    const float* __restrict__ x, const int* __restrict__ pidx,
    const float* __restrict__ b2, const char* __restrict__ ws,
    float* __restrict__ out)
{
  __shared__ uint4 sB2[2048];   // 32 KB: W2 B-fragments [frag(kk*8+n)][lane]
  __shared__ uint4 sW1[512];    //  8 KB: W1 B-fragments [frag n][lane]
  __shared__ uint4 sH1[2048];   // 32 KB: per-wave 4KB h1 tile (bf16, swizzled)

  const int bid = blockIdx.x;
  const int tid = threadIdx.x;

  // ---- stage pre-packed fragments into LDS (5 x 16B per thread) ----
  const uint4* W2f = (const uint4*)(ws + WSOFF_W2F);
  const uint4* W1f = (const uint4*)(ws + WSOFF_W1F);
  #pragma unroll
  for (int i = 0; i < 4; i++) sB2[i*512 + tid] = W2f[i*512 + tid];
  sW1[tid] = W1f[tid];
  __syncthreads();

  const int lane = tid & 63;
  const int wv   = tid >> 6;
  const int r15  = lane & 15;
  const int g    = lane >> 4;
  const float* G1 = (const float*)ws;
  const float4* src4 = (const float4*)x;
  float4* dst4 = (float4*)out;

  char* h1base = (char*)sH1 + wv*4096;
  const bf16x8* B2f = (const bf16x8*)sB2;
  const bf16x8* B1f = (const bf16x8*)sW1;

  const int w    = bid*8 + wv;        // global wave id, owns rows w*64..w*64+63
  const int gtid = bid*512 + tid;     // copy lane

  // all 4 tile indices up front (independent loads)
  int idx4[4];
  #pragma unroll
  for (int t = 0; t < 4; t++) idx4[t] = pidx[w*64 + t*16 + r15];

  // prologue prefetch for tile 0: x-row fragment + G1 row
  const float* ap0 = x + idx4[0]*NF + 8*g;
  float4 a0 = *(const float4*)ap0;
  float4 a1 = *(const float4*)(ap0 + 4);
  f32x4 g1n[8];
  {
    const float* gp = G1 + (idx4[0] & (BATCH-1))*DOUT + 4*g;
    #pragma unroll
    for (int n = 0; n < 8; n++) g1n[n] = *(const f32x4*)(gp + 16*n);
  }

  #pragma unroll
  for (int t = 0; t < 4; t++){
    const int row0 = w*64 + t*16;
    const int idxA = idx4[t];

    // copy loads (independent bandwidth work, consumed at iter end)
    float4 cp0 = src4[(t*3+0)*(NMLP*512) + gtid];
    float4 cp1 = src4[(t*3+1)*(NMLP*512) + gtid];
    float4 cp2 = src4[(t*3+2)*(NMLP*512) + gtid];

    // convert A-fragment (cols 8g..8g+7 of this lane's batch row)
    union { bf16x8 v; __hip_bfloat162 h[4]; } af;
    af.h[0] = __float22bfloat162_rn(make_float2(a0.x, a0.y));
    af.h[1] = __float22bfloat162_rn(make_float2(a0.z, a0.w));
    af.h[2] = __float22bfloat162_rn(make_float2(a1.x, a1.y));
    af.h[3] = __float22bfloat162_rn(make_float2(a1.z, a1.w));

    // acc1 takes the prefetched G1 row (bias + global half folded in)
    f32x4 acc1[8];
    #pragma unroll
    for (int n = 0; n < 8; n++) acc1[n] = g1n[n];

    // prefetch next tile's x-row while MFMA1 runs
    float4 a0n = a0, a1n = a1;
    if (t < 3){
      const float* apn = x + idx4[t+1]*NF + 8*g;
      a0n = *(const float4*)apn;
      a1n = *(const float4*)(apn + 4);
    }

    // GEMM1 (transposed): acc1[n][r] = h1[r15][16n+4g+r]
    #pragma unroll
    for (int n = 0; n < 8; n++)
      acc1[n] = __builtin_amdgcn_mfma_f32_16x16x32_bf16(B1f[n*64 + lane], af.v, acc1[n], 0, 0, 0);

    // leaky-relu, pack, ds_write_b64 into swizzled wave-private [16][128] tile
    #pragma unroll
    for (int n = 0; n < 8; n++){
      float v0 = acc1[n][0], v1 = acc1[n][1], v2 = acc1[n][2], v3 = acc1[n][3];
      v0 = v0 > 0.f ? v0 : 0.01f*v0;
      v1 = v1 > 0.f ? v1 : 0.01f*v1;
      v2 = v2 > 0.f ? v2 : 0.01f*v2;
      v3 = v3 > 0.f ? v3 : 0.01f*v3;
      union { uint2 q; __hip_bfloat162 h[2]; } pk;
      pk.h[0] = __float22bfloat162_rn(make_float2(v0, v1));
      pk.h[1] = __float22bfloat162_rn(make_float2(v2, v3));
      int off = r15*256 + (16*n + 4*g)*2;
      off ^= (r15 & 7) << 4;
      *(uint2*)(h1base + off) = pk.q;
    }
    // wave-private LDS tile: compiler orders via lgkmcnt; no barrier needed.

    // prefetch next tile's G1 row while GEMM2 runs
    if (t < 3){
      const float* gp = G1 + (idx4[t+1] & (BATCH-1))*DOUT + 4*g;
      #pragma unroll
      for (int n = 0; n < 8; n++) g1n[n] = *(const f32x4*)(gp + 16*n);
    }

    // residual scalars (col 4n+g of this lane's row; L1/L2-hot) — issue early
    float xres[8];
    #pragma unroll
    for (int n = 0; n < 8; n++) xres[n] = x[idxA*NF + 4*n + g];

    // GEMM2 (transposed): acc2[n][r] = proj[r15][16n+4g+r], b2 folded into init
    f32x4 acc2[8];
    #pragma unroll
    for (int n = 0; n < 8; n++)
      acc2[n] = *(const f32x4*)(b2 + 16*n + 4*g);
    #pragma unroll
    for (int kk = 0; kk < 4; kk++){
      int roff = r15*256 + 64*kk + 16*g;
      roff ^= (r15 & 7) << 4;
      bf16x8 a2 = *(const bf16x8*)(h1base + roff);
      #pragma unroll
      for (int n = 0; n < 8; n++)
        acc2[n] = __builtin_amdgcn_mfma_f32_16x16x32_bf16(B2f[(kk*8 + n)*64 + lane], a2, acc2[n], 0, 0, 0);
    }

    // epilogue: + repeat_interleave residual, float4 store to children layout
    const int p  = row0 >> 11;             // parent (tiles never cross parents)
    const int b0 = row0 & (BATCH-1);
    const int orow = CHBASE + ((p*NBR)*BATCH + b0 + r15)*NF;
    #pragma unroll
    for (int n = 0; n < 8; n++){
      int c0 = 16*n + 4*g;                 // first of 4 consecutive output cols
      int br = c0 >> 5, fc0 = c0 & 31;
      f32x4 v = acc2[n];
      float rsd = xres[n];
      v[0] += rsd; v[1] += rsd; v[2] += rsd; v[3] += rsd;
      *(f32x4*)(out + orow + br*(BATCH*NF) + fc0) = v;
    }

    // copy stores
    dst4[(t*3+0)*(NMLP*512) + gtid] = cp0;
    dst4[(t*3+1)*(NMLP*512) + gtid] = cp1;
    dst4[(t*3+2)*(NMLP*512) + gtid] = cp2;

    a0 = a0n; a1 = a1n;
  }
}

extern "C" void kernel_launch(void* const* d_in, const int* in_sizes, int n_in,
                              void* d_out, int out_size, void* d_ws, size_t ws_size,
                              hipStream_t stream){
  const float* x   = (const float*)d_in[0];
  const float* gf  = (const float*)d_in[1];
  const int*   pidx= (const int*)d_in[2];
  const float* W1  = (const float*)d_in[3];
  const float* b1  = (const float*)d_in[4];
  const float* W2  = (const float*)d_in[5];
  const float* b2  = (const float*)d_in[6];
  float* out = (float*)d_out;
  char* ws   = (char*)d_ws;               // 1MB G1 + 40KB packed fragments

  k_g1  <<<1034, 256, 0, stream>>>(gf, W1, b1, W2, ws);
  k_main<<<NMLP, 512, 0, stream>>>(x, pidx, b2, ws, out);
}